// Round 7
// baseline (1145.088 us; speedup 1.0000x reference)
//
#include <hip/hip_runtime.h>
#include <hip/hip_bf16.h>

// SimpleRNN: B=64, S=2048, IN=256, H=128, OUT=3 (all fp32)
// Phase 1: xproj = x @ W_xh^T + b_xh -> d_ws (64 MiB)  [byte-identical]
// Phase 2: scan, 64 blocks x 512 threads (8 waves), 1 LDS-only barrier/step.
//   Round-6 post-mortem: conflicts fixed (-180us as modeled) but 900 cyc/step
//   remains: (a) allocator pins itself under the 64-VGPR occupancy boundary
//   and spills (VGPR=40 < 32 weights + working set); (b) h-broadcast moved
//   64 KB/step through the LDS return path (16x duplication).
//   Round-7 redesign: thread owns 2 rows x 16-wide K-slice (8-lane groups):
//   - per-CU h traffic halves to 32 KB/step;
//   - working set ~58 VGPRs fits UNDER 64 -> no spill at max-occupancy target;
//   - h stored in 8 groups of 16 floats padded to 20 (80 B, 16B-aligned):
//     group bases hit disjoint bank quads -> conflict-free b128 reads.

#define RNN_B   64
#define RNN_S   2048
#define RNN_IN  256
#define RNN_H   128
#define RNN_OUT 3

// LDS h layout: k = 16*grp + m  ->  pos = 20*grp + m   (pads at +16..19)
#define HPOS(k) (20 * ((k) >> 4) + ((k) & 15))

// ---------------------------------------------------------------------------
// Phase 1: fp32 tiled GEMM  C[M=131072, N=128] = A[M,256] * B[128,256]^T
// (byte-identical to rounds 2-6 for attribution)
// ---------------------------------------------------------------------------
__global__ __launch_bounds__(256) void xproj_gemm(
    const float* __restrict__ x, const float* __restrict__ Wxh,
    const float* __restrict__ bxh, float* __restrict__ xp) {
  __shared__ __align__(16) float As[32][132];  // [k][m]
  __shared__ __align__(16) float Bs[32][132];  // [k][n]

  const int tid = threadIdx.x;
  const int m0 = blockIdx.x * 128;
  const int tn = (tid & 15) * 8;   // n offset 0..120
  const int tm = (tid >> 4) * 8;   // m offset 0..120

  float acc[8][8];
#pragma unroll
  for (int i = 0; i < 8; ++i)
#pragma unroll
    for (int j = 0; j < 8; ++j) acc[i][j] = 0.f;

  const int c = (tid & 7) * 4;   // k sub-col (float4)
  const int r0 = tid >> 3;       // row 0..31

  for (int kc = 0; kc < RNN_IN; kc += 32) {
#pragma unroll
    for (int p = 0; p < 4; ++p) {
      const int row = r0 + 32 * p;
      const float4 va = *(const float4*)&x[(size_t)(m0 + row) * RNN_IN + kc + c];
      As[c + 0][row] = va.x; As[c + 1][row] = va.y;
      As[c + 2][row] = va.z; As[c + 3][row] = va.w;
      const float4 vb = *(const float4*)&Wxh[(size_t)row * RNN_IN + kc + c];
      Bs[c + 0][row] = vb.x; Bs[c + 1][row] = vb.y;
      Bs[c + 2][row] = vb.z; Bs[c + 3][row] = vb.w;
    }
    __syncthreads();
#pragma unroll
    for (int k = 0; k < 32; ++k) {
      const float4 a0 = *(const float4*)&As[k][tm];
      const float4 a1 = *(const float4*)&As[k][tm + 4];
      const float4 b0 = *(const float4*)&Bs[k][tn];
      const float4 b1 = *(const float4*)&Bs[k][tn + 4];
      const float a[8] = {a0.x, a0.y, a0.z, a0.w, a1.x, a1.y, a1.z, a1.w};
      const float b[8] = {b0.x, b0.y, b0.z, b0.w, b1.x, b1.y, b1.z, b1.w};
#pragma unroll
      for (int i = 0; i < 8; ++i)
#pragma unroll
        for (int j = 0; j < 8; ++j) acc[i][j] += a[i] * b[j];
    }
    __syncthreads();
  }

#pragma unroll
  for (int i = 0; i < 8; ++i) {
    const size_t row = (size_t)(m0 + tm + i);
#pragma unroll
    for (int j = 0; j < 8; j += 4) {
      float4 v;
      v.x = acc[i][j + 0] + bxh[tn + j + 0];
      v.y = acc[i][j + 1] + bxh[tn + j + 1];
      v.z = acc[i][j + 2] + bxh[tn + j + 2];
      v.w = acc[i][j + 3] + bxh[tn + j + 3];
      *(float4*)&xp[row * RNN_H + tn + j] = v;
    }
  }
}

// fast tanh: 1 - 2/(exp(2x)+1); saturates correctly at +-inf
__device__ __forceinline__ float fast_tanh(float a) {
  const float e = __expf(2.f * a);
  return 1.f - 2.f / (e + 1.f);
}

// LDS-only barrier: does NOT drain vmcnt (HIP __syncthreads emits vmcnt(0)),
// so global prefetch loads stay in flight across the barrier.
__device__ __forceinline__ void block_sync_lds() {
  asm volatile("s_waitcnt lgkmcnt(0)" ::: "memory");
  __builtin_amdgcn_s_barrier();
}

// One step: thread (rows r0,r0+1; k-group g) reads its 16-float k-slice of
// old h from BIN (4 x ds_read_b128; 8 group bases on disjoint bank quads,
// 8-lane broadcast each -> conflict-free), 32 FMAs from register weights,
// 8-lane butterfly reduction (3x shfl_xor per row), tanh, g==0 lane writes
// float2 to BOUT, single LDS-only barrier. PREG (float2) consumed early then
// refilled with xp rows at TNEXT (stays in flight ~4 steps).
#define RNN_STEP(BIN, BOUT, PREG, TNEXT)                                   \
  {                                                                        \
    const float4* hq = (const float4*)(BIN) + 5 * g;                       \
    const float2 xin = PREG;                                               \
    PREG = *(const float2*)&xpb[(size_t)(TNEXT) * RNN_H + r0];             \
    float a0 = 0.f, b0 = 0.f, a1 = 0.f, b1 = 0.f;                          \
    {                                                                      \
      const float4 h4 = hq[0];                                             \
      a0 = fmaf(w00.x, h4.x, a0); a1 = fmaf(w10.x, h4.x, a1);              \
      a0 = fmaf(w00.y, h4.y, a0); a1 = fmaf(w10.y, h4.y, a1);              \
      a0 = fmaf(w00.z, h4.z, a0); a1 = fmaf(w10.z, h4.z, a1);              \
      a0 = fmaf(w00.w, h4.w, a0); a1 = fmaf(w10.w, h4.w, a1);              \
    }                                                                      \
    {                                                                      \
      const float4 h4 = hq[1];                                             \
      b0 = fmaf(w01.x, h4.x, b0); b1 = fmaf(w11.x, h4.x, b1);              \
      b0 = fmaf(w01.y, h4.y, b0); b1 = fmaf(w11.y, h4.y, b1);              \
      b0 = fmaf(w01.z, h4.z, b0); b1 = fmaf(w11.z, h4.z, b1);              \
      b0 = fmaf(w01.w, h4.w, b0); b1 = fmaf(w11.w, h4.w, b1);              \
    }                                                                      \
    {                                                                      \
      const float4 h4 = hq[2];                                             \
      a0 = fmaf(w02.x, h4.x, a0); a1 = fmaf(w12.x, h4.x, a1);              \
      a0 = fmaf(w02.y, h4.y, a0); a1 = fmaf(w12.y, h4.y, a1);              \
      a0 = fmaf(w02.z, h4.z, a0); a1 = fmaf(w12.z, h4.z, a1);              \
      a0 = fmaf(w02.w, h4.w, a0); a1 = fmaf(w12.w, h4.w, a1);              \
    }                                                                      \
    {                                                                      \
      const float4 h4 = hq[3];                                             \
      b0 = fmaf(w03.x, h4.x, b0); b1 = fmaf(w13.x, h4.x, b1);              \
      b0 = fmaf(w03.y, h4.y, b0); b1 = fmaf(w13.y, h4.y, b1);              \
      b0 = fmaf(w03.z, h4.z, b0); b1 = fmaf(w13.z, h4.z, b1);              \
      b0 = fmaf(w03.w, h4.w, b0); b1 = fmaf(w13.w, h4.w, b1);              \
    }                                                                      \
    float s0 = a0 + b0, s1 = a1 + b1;                                      \
    s0 += __shfl_xor(s0, 1, 64); s1 += __shfl_xor(s1, 1, 64);              \
    s0 += __shfl_xor(s0, 2, 64); s1 += __shfl_xor(s1, 2, 64);              \
    s0 += __shfl_xor(s0, 4, 64); s1 += __shfl_xor(s1, 4, 64);              \
    const float hv0 = fast_tanh(bias0 + xin.x + s0);                       \
    const float hv1 = fast_tanh(bias1 + xin.y + s1);                       \
    if (g == 0) *(float2*)((BOUT) + wpos) = make_float2(hv0, hv1);         \
    block_sync_lds();                                                      \
  }

// ---------------------------------------------------------------------------
// Phase 2: recurrence. grid=64 blocks, block=512 threads (8 waves).
// lane = rp*8 + g: 8-lane group (g=0..7) covers K=128 for rows r0=wv*16+2rp,
// r0+1. Thread holds W_hh[r0..r0+1, 16g..16g+15] in 8 float4 regs (~58 VGPR
// working set -- under the 64-VGPR occupancy boundary the allocator targets).
// h double-buffered in padded LDS; 1 barrier/step; 4-deep float2 prefetch.
// ---------------------------------------------------------------------------
__global__ __launch_bounds__(512, 2) void rnn_scan(
    const float* __restrict__ xp, const float* __restrict__ Whh,
    const float* __restrict__ bhh, const float* __restrict__ bh,
    const float* __restrict__ Wfc, const float* __restrict__ bfc,
    float* __restrict__ out) {
  const int b = blockIdx.x;
  const int tid = threadIdx.x;         // 0..511
  const int wv = tid >> 6;             // wave 0..7
  const int lane = tid & 63;
  const int g = lane & 7;              // k-group (16 floats)
  const int rp = lane >> 3;            // row-pair 0..7 within wave
  const int r0 = wv * 16 + 2 * rp;     // first owned row

  __shared__ __align__(16) float hsA[8 * 20];
  __shared__ __align__(16) float hsB[8 * 20];

  // weights: rows r0, r0+1, cols [16g, 16g+16) -> 8 float4 registers
  const float4* w0p = (const float4*)&Whh[(size_t)r0 * RNN_H + 16 * g];
  const float4* w1p = (const float4*)&Whh[(size_t)(r0 + 1) * RNN_H + 16 * g];
  const float4 w00 = w0p[0], w01 = w0p[1], w02 = w0p[2], w03 = w0p[3];
  const float4 w10 = w1p[0], w11 = w1p[1], w12 = w1p[2], w13 = w1p[3];

  const float bias0 = bhh[r0] + bh[r0];
  const float bias1 = bhh[r0 + 1] + bh[r0 + 1];

  if (tid < 160) hsA[tid] = 0.f;   // zero h + pads
  block_sync_lds();

  const float* xpb = xp + (size_t)b * RNN_S * RNN_H;
  const int wpos = 20 * wv + 2 * rp;   // LDS write position for rows r0,r0+1

  // 4-deep float2 prefetch, one register per unrolled body
  float2 p0 = *(const float2*)&xpb[0 * RNN_H + r0];
  float2 p1 = *(const float2*)&xpb[1 * RNN_H + r0];
  float2 p2 = *(const float2*)&xpb[2 * RNN_H + r0];
  float2 p3 = *(const float2*)&xpb[3 * RNN_H + r0];

#pragma unroll 1
  for (int t = 0; t < RNN_S; t += 4) {
    const int n0 = (t + 4 < RNN_S) ? t + 4 : RNN_S - 1;
    const int n1 = (t + 5 < RNN_S) ? t + 5 : RNN_S - 1;
    const int n2 = (t + 6 < RNN_S) ? t + 6 : RNN_S - 1;
    const int n3 = (t + 7 < RNN_S) ? t + 7 : RNN_S - 1;
    RNN_STEP(hsA, hsB, p0, n0)
    RNN_STEP(hsB, hsA, p1, n1)
    RNN_STEP(hsA, hsB, p2, n2)
    RNN_STEP(hsB, hsA, p3, n3)
  }
  // 2048 steps: last body writes hsA; trailing block_sync_lds made it visible.

  // fused FC: out[b][o] = sum_k hs[k] * Wfc[o][k] + bfc[o]
  if (tid < RNN_OUT) {
    float s = bfc[tid];
#pragma unroll 4
    for (int k = 0; k < RNN_H; ++k)
      s = fmaf(Wfc[(size_t)tid * RNN_H + k], hsA[HPOS(k)], s);
    out[b * RNN_OUT + tid] = s;
  }
}

extern "C" void kernel_launch(void* const* d_in, const int* in_sizes, int n_in,
                              void* d_out, int out_size, void* d_ws, size_t ws_size,
                              hipStream_t stream) {
  const float* x   = (const float*)d_in[0];
  const float* Wxh = (const float*)d_in[1];
  const float* bxh = (const float*)d_in[2];
  const float* Whh = (const float*)d_in[3];
  const float* bhh = (const float*)d_in[4];
  const float* bh  = (const float*)d_in[5];
  const float* Wfc = (const float*)d_in[6];
  const float* bfc = (const float*)d_in[7];
  float* out = (float*)d_out;
  float* xp  = (float*)d_ws;  // 131072*128*4 = 64 MiB

  xproj_gemm<<<dim3((RNN_B * RNN_S) / 128), dim3(256), 0, stream>>>(x, Wxh, bxh, xp);
  rnn_scan<<<dim3(RNN_B), dim3(512), 0, stream>>>(xp, Whh, bhh, bh, Wfc, bfc, out);
}

// Round 8
// 890.109 us; speedup vs baseline: 1.2865x; 1.2865x over previous
//
#include <hip/hip_runtime.h>
#include <hip/hip_bf16.h>
#include <hip/hip_fp16.h>

// SimpleRNN: B=64, S=2048, IN=256, H=128, OUT=3 (all fp32)
// Phase 1: xproj = x @ W_xh^T + b_xh -> d_ws (64 MiB)  [byte-identical]
// Phase 2: scan, 64 blocks x 512 threads (8 waves), 1 LDS-only barrier/step.
//   r6: LDS-issue-bound (64 b128/step ~= 770 cyc). r7: latency-chain-bound
//   (+4 shfl, +1 exp, spills; traffic slack unused). r8: f16 matvec via
//   v_dot2_f32_f16 (fp32 accumulate):
//   - w: 16 half2 VGPRs -> working set ~36 regs, UNDER the ~40-VGPR envelope
//     the allocator demonstrably grants -> no spill by construction;
//   - h as f16 in LDS: 4 b128/thread/step (r6's bottleneck halved), slice
//     stride 80 B -> disjoint bank quads -> 0 conflicts;
//   - chain back to r6 shape: 2 shfls, 1 tanh.
//   Numerics: only w,h f16; xp/bias/acc fp32. Fallback if absmax>thr: fp32 h.

#define RNN_B   64
#define RNN_S   2048
#define RNN_IN  256
#define RNN_H   128
#define RNN_OUT 3

typedef _Float16 half2v __attribute__((ext_vector_type(2)));

#if __has_builtin(__builtin_amdgcn_fdot2)
#define FDOT2(a, b, c) __builtin_amdgcn_fdot2((a), (b), (c), false)
#else
#define FDOT2(a, b, c) \
  fmaf((float)(a).x, (float)(b).x, fmaf((float)(a).y, (float)(b).y, (c)))
#endif

// h LDS layout (f16): slice q = k>>5 (32 halves = 64 B) stored at byte
// 80*q (pad 16 B per slice). Half-index: HPOSH(k) = 40*(k>>5) + (k&31).
// b128 read addrs per wave-instr: 80q+16i -> dword-banks {0,20,8,28}+4i:
// disjoint bank quads -> conflict-free.
#define HPOSH(k) (40 * ((k) >> 5) + ((k) & 31))

// ---------------------------------------------------------------------------
// Phase 1: fp32 tiled GEMM  C[M=131072, N=128] = A[M,256] * B[128,256]^T
// (byte-identical to rounds 2-7 for attribution)
// ---------------------------------------------------------------------------
__global__ __launch_bounds__(256) void xproj_gemm(
    const float* __restrict__ x, const float* __restrict__ Wxh,
    const float* __restrict__ bxh, float* __restrict__ xp) {
  __shared__ __align__(16) float As[32][132];  // [k][m]
  __shared__ __align__(16) float Bs[32][132];  // [k][n]

  const int tid = threadIdx.x;
  const int m0 = blockIdx.x * 128;
  const int tn = (tid & 15) * 8;   // n offset 0..120
  const int tm = (tid >> 4) * 8;   // m offset 0..120

  float acc[8][8];
#pragma unroll
  for (int i = 0; i < 8; ++i)
#pragma unroll
    for (int j = 0; j < 8; ++j) acc[i][j] = 0.f;

  const int c = (tid & 7) * 4;   // k sub-col (float4)
  const int r0 = tid >> 3;       // row 0..31

  for (int kc = 0; kc < RNN_IN; kc += 32) {
#pragma unroll
    for (int p = 0; p < 4; ++p) {
      const int row = r0 + 32 * p;
      const float4 va = *(const float4*)&x[(size_t)(m0 + row) * RNN_IN + kc + c];
      As[c + 0][row] = va.x; As[c + 1][row] = va.y;
      As[c + 2][row] = va.z; As[c + 3][row] = va.w;
      const float4 vb = *(const float4*)&Wxh[(size_t)row * RNN_IN + kc + c];
      Bs[c + 0][row] = vb.x; Bs[c + 1][row] = vb.y;
      Bs[c + 2][row] = vb.z; Bs[c + 3][row] = vb.w;
    }
    __syncthreads();
#pragma unroll
    for (int k = 0; k < 32; ++k) {
      const float4 a0 = *(const float4*)&As[k][tm];
      const float4 a1 = *(const float4*)&As[k][tm + 4];
      const float4 b0 = *(const float4*)&Bs[k][tn];
      const float4 b1 = *(const float4*)&Bs[k][tn + 4];
      const float a[8] = {a0.x, a0.y, a0.z, a0.w, a1.x, a1.y, a1.z, a1.w};
      const float b[8] = {b0.x, b0.y, b0.z, b0.w, b1.x, b1.y, b1.z, b1.w};
#pragma unroll
      for (int i = 0; i < 8; ++i)
#pragma unroll
        for (int j = 0; j < 8; ++j) acc[i][j] += a[i] * b[j];
    }
    __syncthreads();
  }

#pragma unroll
  for (int i = 0; i < 8; ++i) {
    const size_t row = (size_t)(m0 + tm + i);
#pragma unroll
    for (int j = 0; j < 8; j += 4) {
      float4 v;
      v.x = acc[i][j + 0] + bxh[tn + j + 0];
      v.y = acc[i][j + 1] + bxh[tn + j + 1];
      v.z = acc[i][j + 2] + bxh[tn + j + 2];
      v.w = acc[i][j + 3] + bxh[tn + j + 3];
      *(float4*)&xp[row * RNN_H + tn + j] = v;
    }
  }
}

// fast tanh: 1 - 2/(exp(2x)+1); saturates correctly at +-inf
__device__ __forceinline__ float fast_tanh(float a) {
  const float e = __expf(2.f * a);
  return 1.f - 2.f / (e + 1.f);
}

// LDS-only barrier: does NOT drain vmcnt (HIP __syncthreads emits vmcnt(0)),
// so global prefetch loads stay in flight across the barrier.
__device__ __forceinline__ void block_sync_lds() {
  asm volatile("s_waitcnt lgkmcnt(0)" ::: "memory");
  __builtin_amdgcn_s_barrier();
}

// 16 named half2 weight registers per thread (32 f16 = quarter W_hh row).
#define RNN_W_LIST(M) \
  M(0)  M(1)  M(2)  M(3)  M(4)  M(5)  M(6)  M(7)  \
  M(8)  M(9)  M(10) M(11) M(12) M(13) M(14) M(15)

#define WDECL(i) half2v w##i;
#define WLOADH(i)                                   \
  {                                                 \
    half2v _t;                                      \
    _t.x = (_Float16)wr[2 * (i)];                   \
    _t.y = (_Float16)wr[2 * (i) + 1];               \
    w##i = _t;                                      \
  }

// One step: thread (row r, quarter q) reads its 32-half k-slice of old h
// from BIN (4 x ds_read_b128, conflict-free by 80-B slice stride), 16
// full-rate v_dot2_f32_f16 with fp32 accumulate, 4-lane butterfly reduction
// (2x shfl_xor), tanh in fp32, q==0 lane writes f16 h[r] to BOUT, single
// LDS-only barrier. PREG consumed early then refilled with xp[TNEXT]
// (fp32; stays in flight ~4 steps; barrier never drains vmcnt).
#define RNN_STEP(BIN, BOUT, PREG, TNEXT)                              \
  {                                                                  \
    const float4* hq = (const float4*)(BIN) + 5 * q;                 \
    const float xin = PREG;                                          \
    PREG = xpb[(size_t)(TNEXT) * RNN_H + r];                         \
    union { float4 f4; half2v h[4]; } u0, u1, u2, u3;                \
    u0.f4 = hq[0]; u1.f4 = hq[1]; u2.f4 = hq[2]; u3.f4 = hq[3];      \
    float acc0 = 0.f, acc1 = 0.f, acc2 = 0.f, acc3 = 0.f;            \
    acc0 = FDOT2(w0,  u0.h[0], acc0);                                \
    acc1 = FDOT2(w1,  u0.h[1], acc1);                                \
    acc2 = FDOT2(w2,  u0.h[2], acc2);                                \
    acc3 = FDOT2(w3,  u0.h[3], acc3);                                \
    acc0 = FDOT2(w4,  u1.h[0], acc0);                                \
    acc1 = FDOT2(w5,  u1.h[1], acc1);                                \
    acc2 = FDOT2(w6,  u1.h[2], acc2);                                \
    acc3 = FDOT2(w7,  u1.h[3], acc3);                                \
    acc0 = FDOT2(w8,  u2.h[0], acc0);                                \
    acc1 = FDOT2(w9,  u2.h[1], acc1);                                \
    acc2 = FDOT2(w10, u2.h[2], acc2);                                \
    acc3 = FDOT2(w11, u2.h[3], acc3);                                \
    acc0 = FDOT2(w12, u3.h[0], acc0);                                \
    acc1 = FDOT2(w13, u3.h[1], acc1);                                \
    acc2 = FDOT2(w14, u3.h[2], acc2);                                \
    acc3 = FDOT2(w15, u3.h[3], acc3);                                \
    float s = (acc0 + acc1) + (acc2 + acc3);                         \
    s += __shfl_xor(s, 1, 64);                                       \
    s += __shfl_xor(s, 2, 64);                                       \
    const float hv = fast_tanh(bias + xin + s);                      \
    if (q == 0) ((_Float16*)(BOUT))[hw] = (_Float16)hv;              \
    block_sync_lds();                                                \
  }

// ---------------------------------------------------------------------------
// Phase 2: recurrence. grid=64 blocks, block=512 threads (8 waves).
// Aligned 4-lane group owns row r = 16*wave + (lane>>2); thread holds
// W_hh[r, 32q..32q+31] as 16 half2 regs (~36 VGPR working set, under the
// ~40-reg envelope). h (f16) double-buffered in padded LDS; 1 barrier/step.
// ---------------------------------------------------------------------------
__global__ __launch_bounds__(512, 2) void rnn_scan(
    const float* __restrict__ xp, const float* __restrict__ Whh,
    const float* __restrict__ bhh, const float* __restrict__ bh,
    const float* __restrict__ Wfc, const float* __restrict__ bfc,
    float* __restrict__ out) {
  const int b = blockIdx.x;
  const int tid = threadIdx.x;        // 0..511
  const int wv = tid >> 6;            // wave 0..7
  const int lane = tid & 63;
  const int q = lane & 3;             // k-quarter (32 halves)
  const int r = wv * 16 + (lane >> 2);  // row 0..127

  // 4 slices x 80 B = 320 B per buffer, float4-typed for b128 access
  __shared__ float4 hsA[20];
  __shared__ float4 hsB[20];

  const float* wr = &Whh[(size_t)r * RNN_H + 32 * q];
  RNN_W_LIST(WDECL)
  RNN_W_LIST(WLOADH)

  const float bias = bhh[r] + bh[r];
  const int hw = HPOSH(r);            // f16 write slot for row r

  // zero both h buffers incl. pads (80 floats = 320 B each)
  if (tid < 80) ((float*)hsA)[tid] = 0.f;
  block_sync_lds();

  const float* xpb = xp + (size_t)b * RNN_S * RNN_H;

  // 4-deep fp32 prefetch, one register per unrolled body
  float p0 = xpb[0 * RNN_H + r];
  float p1 = xpb[1 * RNN_H + r];
  float p2 = xpb[2 * RNN_H + r];
  float p3 = xpb[3 * RNN_H + r];

#pragma unroll 1
  for (int t = 0; t < RNN_S; t += 4) {
    const int n0 = (t + 4 < RNN_S) ? t + 4 : RNN_S - 1;
    const int n1 = (t + 5 < RNN_S) ? t + 5 : RNN_S - 1;
    const int n2 = (t + 6 < RNN_S) ? t + 6 : RNN_S - 1;
    const int n3 = (t + 7 < RNN_S) ? t + 7 : RNN_S - 1;
    RNN_STEP(hsA, hsB, p0, n0)
    RNN_STEP(hsB, hsA, p1, n1)
    RNN_STEP(hsA, hsB, p2, n2)
    RNN_STEP(hsB, hsA, p3, n3)
  }
  // 2048 steps: last body writes hsA; trailing block_sync_lds made it visible.

  // fused FC: out[b][o] = sum_k hs[k] * Wfc[o][k] + bfc[o]
  if (tid < RNN_OUT) {
    float s = bfc[tid];
    const _Float16* hf = (const _Float16*)hsA;
#pragma unroll 4
    for (int k = 0; k < RNN_H; ++k)
      s = fmaf(Wfc[(size_t)tid * RNN_H + k], (float)hf[HPOSH(k)], s);
    out[b * RNN_OUT + tid] = s;
  }
}

extern "C" void kernel_launch(void* const* d_in, const int* in_sizes, int n_in,
                              void* d_out, int out_size, void* d_ws, size_t ws_size,
                              hipStream_t stream) {
  const float* x   = (const float*)d_in[0];
  const float* Wxh = (const float*)d_in[1];
  const float* bxh = (const float*)d_in[2];
  const float* Whh = (const float*)d_in[3];
  const float* bhh = (const float*)d_in[4];
  const float* bh  = (const float*)d_in[5];
  const float* Wfc = (const float*)d_in[6];
  const float* bfc = (const float*)d_in[7];
  float* out = (float*)d_out;
  float* xp  = (float*)d_ws;  // 131072*128*4 = 64 MiB

  xproj_gemm<<<dim3((RNN_B * RNN_S) / 128), dim3(256), 0, stream>>>(x, Wxh, bxh, xp);
  rnn_scan<<<dim3(RNN_B), dim3(512), 0, stream>>>(xp, Whh, bhh, bh, Wfc, bfc, out);
}

// Round 9
// 827.366 us; speedup vs baseline: 1.3840x; 1.0758x over previous
//
#include <hip/hip_runtime.h>
#include <hip/hip_bf16.h>
#include <hip/hip_fp16.h>

// SimpleRNN: B=64, S=2048, IN=256, H=128, OUT=3 (all fp32)
// Phase 1: xproj = x @ W_xh^T + b_xh -> d_ws (64 MiB)  [byte-identical]
// Phase 2: scan, 64 blocks x 512 threads (8 waves), 1 LDS-only barrier/step.
//   r8 landed f16 dot2 + spill-free regs (VGPR=32): 790 cyc/step.
//   r9: __shfl_xor lowers to ds_bpermute (DS crossbar, ~65 cyc latency each)
//   -> replace the 4-lane reduction with DPP quad_perm adds (VALU, ~4 cyc):
//   removes ~130 cyc from the serial chain + 16 DS instrs/CU/step.

#define RNN_B   64
#define RNN_S   2048
#define RNN_IN  256
#define RNN_H   128
#define RNN_OUT 3

typedef _Float16 half2v __attribute__((ext_vector_type(2)));

#if __has_builtin(__builtin_amdgcn_fdot2)
#define FDOT2(a, b, c) __builtin_amdgcn_fdot2((a), (b), (c), false)
#else
#define FDOT2(a, b, c) \
  fmaf((float)(a).x, (float)(b).x, fmaf((float)(a).y, (float)(b).y, (c)))
#endif

// h LDS layout (f16): slice q = k>>5 (32 halves = 64 B) stored at byte
// 80*q (pad 16 B per slice). Half-index: HPOSH(k) = 40*(k>>5) + (k&31).
#define HPOSH(k) (40 * ((k) >> 5) + ((k) & 31))

// ---------------------------------------------------------------------------
// Phase 1: fp32 tiled GEMM  C[M=131072, N=128] = A[M,256] * B[128,256]^T
// (byte-identical to rounds 2-8 for attribution)
// ---------------------------------------------------------------------------
__global__ __launch_bounds__(256) void xproj_gemm(
    const float* __restrict__ x, const float* __restrict__ Wxh,
    const float* __restrict__ bxh, float* __restrict__ xp) {
  __shared__ __align__(16) float As[32][132];  // [k][m]
  __shared__ __align__(16) float Bs[32][132];  // [k][n]

  const int tid = threadIdx.x;
  const int m0 = blockIdx.x * 128;
  const int tn = (tid & 15) * 8;   // n offset 0..120
  const int tm = (tid >> 4) * 8;   // m offset 0..120

  float acc[8][8];
#pragma unroll
  for (int i = 0; i < 8; ++i)
#pragma unroll
    for (int j = 0; j < 8; ++j) acc[i][j] = 0.f;

  const int c = (tid & 7) * 4;   // k sub-col (float4)
  const int r0 = tid >> 3;       // row 0..31

  for (int kc = 0; kc < RNN_IN; kc += 32) {
#pragma unroll
    for (int p = 0; p < 4; ++p) {
      const int row = r0 + 32 * p;
      const float4 va = *(const float4*)&x[(size_t)(m0 + row) * RNN_IN + kc + c];
      As[c + 0][row] = va.x; As[c + 1][row] = va.y;
      As[c + 2][row] = va.z; As[c + 3][row] = va.w;
      const float4 vb = *(const float4*)&Wxh[(size_t)row * RNN_IN + kc + c];
      Bs[c + 0][row] = vb.x; Bs[c + 1][row] = vb.y;
      Bs[c + 2][row] = vb.z; Bs[c + 3][row] = vb.w;
    }
    __syncthreads();
#pragma unroll
    for (int k = 0; k < 32; ++k) {
      const float4 a0 = *(const float4*)&As[k][tm];
      const float4 a1 = *(const float4*)&As[k][tm + 4];
      const float4 b0 = *(const float4*)&Bs[k][tn];
      const float4 b1 = *(const float4*)&Bs[k][tn + 4];
      const float a[8] = {a0.x, a0.y, a0.z, a0.w, a1.x, a1.y, a1.z, a1.w};
      const float b[8] = {b0.x, b0.y, b0.z, b0.w, b1.x, b1.y, b1.z, b1.w};
#pragma unroll
      for (int i = 0; i < 8; ++i)
#pragma unroll
        for (int j = 0; j < 8; ++j) acc[i][j] += a[i] * b[j];
    }
    __syncthreads();
  }

#pragma unroll
  for (int i = 0; i < 8; ++i) {
    const size_t row = (size_t)(m0 + tm + i);
#pragma unroll
    for (int j = 0; j < 8; j += 4) {
      float4 v;
      v.x = acc[i][j + 0] + bxh[tn + j + 0];
      v.y = acc[i][j + 1] + bxh[tn + j + 1];
      v.z = acc[i][j + 2] + bxh[tn + j + 2];
      v.w = acc[i][j + 3] + bxh[tn + j + 3];
      *(float4*)&xp[row * RNN_H + tn + j] = v;
    }
  }
}

// fast tanh: 1 - 2/(exp(2x)+1); saturates correctly at +-inf
__device__ __forceinline__ float fast_tanh(float a) {
  const float e = __expf(2.f * a);
  return 1.f - 2.f / (e + 1.f);
}

// LDS-only barrier: does NOT drain vmcnt (HIP __syncthreads emits vmcnt(0)),
// so global prefetch loads stay in flight across the barrier.
__device__ __forceinline__ void block_sync_lds() {
  asm volatile("s_waitcnt lgkmcnt(0)" ::: "memory");
  __builtin_amdgcn_s_barrier();
}

// 4-lane (quad) sum via DPP quad_perm -- pure VALU (~4 cyc/op), replacing
// __shfl_xor's ds_bpermute (~65 cyc DS-crossbar latency each).
// 0xB1 = quad_perm [1,0,3,2] (xor 1); 0x4E = quad_perm [2,3,0,1] (xor 2).
__device__ __forceinline__ float quad_sum_dpp(float s) {
  int t = __builtin_amdgcn_mov_dpp(__builtin_bit_cast(int, s),
                                   0xB1, 0xF, 0xF, true);
  s += __builtin_bit_cast(float, t);
  t = __builtin_amdgcn_mov_dpp(__builtin_bit_cast(int, s),
                               0x4E, 0xF, 0xF, true);
  s += __builtin_bit_cast(float, t);
  return s;
}

// 16 named half2 weight registers per thread (32 f16 = quarter W_hh row).
#define RNN_W_LIST(M) \
  M(0)  M(1)  M(2)  M(3)  M(4)  M(5)  M(6)  M(7)  \
  M(8)  M(9)  M(10) M(11) M(12) M(13) M(14) M(15)

#define WDECL(i) half2v w##i;
#define WLOADH(i)                                   \
  {                                                 \
    half2v _t;                                      \
    _t.x = (_Float16)wr[2 * (i)];                   \
    _t.y = (_Float16)wr[2 * (i) + 1];               \
    w##i = _t;                                      \
  }

// One step: thread (row r, quarter q) reads its 32-half k-slice of old h
// from BIN (4 x ds_read_b128, conflict-free by 80-B slice stride), 16
// full-rate v_dot2_f32_f16 with fp32 accumulate, DPP quad reduction (VALU),
// tanh in fp32, q==0 lane writes f16 h[r] to BOUT, single LDS-only barrier.
// PREG consumed early then refilled with xp[TNEXT] (fp32; stays in flight
// ~4 steps; barrier never drains vmcnt).
#define RNN_STEP(BIN, BOUT, PREG, TNEXT)                              \
  {                                                                  \
    const float4* hq = (const float4*)(BIN) + 5 * q;                 \
    const float xin = PREG;                                          \
    PREG = xpb[(size_t)(TNEXT) * RNN_H + r];                         \
    union { float4 f4; half2v h[4]; } u0, u1, u2, u3;                \
    u0.f4 = hq[0]; u1.f4 = hq[1]; u2.f4 = hq[2]; u3.f4 = hq[3];      \
    float acc0 = 0.f, acc1 = 0.f, acc2 = 0.f, acc3 = 0.f;            \
    acc0 = FDOT2(w0,  u0.h[0], acc0);                                \
    acc1 = FDOT2(w1,  u0.h[1], acc1);                                \
    acc2 = FDOT2(w2,  u0.h[2], acc2);                                \
    acc3 = FDOT2(w3,  u0.h[3], acc3);                                \
    acc0 = FDOT2(w4,  u1.h[0], acc0);                                \
    acc1 = FDOT2(w5,  u1.h[1], acc1);                                \
    acc2 = FDOT2(w6,  u1.h[2], acc2);                                \
    acc3 = FDOT2(w7,  u1.h[3], acc3);                                \
    acc0 = FDOT2(w8,  u2.h[0], acc0);                                \
    acc1 = FDOT2(w9,  u2.h[1], acc1);                                \
    acc2 = FDOT2(w10, u2.h[2], acc2);                                \
    acc3 = FDOT2(w11, u2.h[3], acc3);                                \
    acc0 = FDOT2(w12, u3.h[0], acc0);                                \
    acc1 = FDOT2(w13, u3.h[1], acc1);                                \
    acc2 = FDOT2(w14, u3.h[2], acc2);                                \
    acc3 = FDOT2(w15, u3.h[3], acc3);                                \
    float s = (acc0 + acc1) + (acc2 + acc3);                         \
    s = quad_sum_dpp(s);                                             \
    const float hv = fast_tanh(bias + xin + s);                      \
    if (q == 0) ((_Float16*)(BOUT))[hw] = (_Float16)hv;              \
    block_sync_lds();                                                \
  }

// ---------------------------------------------------------------------------
// Phase 2: recurrence. grid=64 blocks, block=512 threads (8 waves).
// Aligned 4-lane group owns row r = 16*wave + (lane>>2); thread holds
// W_hh[r, 32q..32q+31] as 16 half2 regs (~36 VGPR working set, spill-free).
// h (f16) double-buffered in padded LDS; 1 barrier/step; 4-deep prefetch.
// ---------------------------------------------------------------------------
__global__ __launch_bounds__(512, 2) void rnn_scan(
    const float* __restrict__ xp, const float* __restrict__ Whh,
    const float* __restrict__ bhh, const float* __restrict__ bh,
    const float* __restrict__ Wfc, const float* __restrict__ bfc,
    float* __restrict__ out) {
  const int b = blockIdx.x;
  const int tid = threadIdx.x;        // 0..511
  const int wv = tid >> 6;            // wave 0..7
  const int lane = tid & 63;
  const int q = lane & 3;             // k-quarter (32 halves)
  const int r = wv * 16 + (lane >> 2);  // row 0..127

  // 4 slices x 80 B = 320 B per buffer, float4-typed for b128 access
  __shared__ float4 hsA[20];
  __shared__ float4 hsB[20];

  const float* wr = &Whh[(size_t)r * RNN_H + 32 * q];
  RNN_W_LIST(WDECL)
  RNN_W_LIST(WLOADH)

  const float bias = bhh[r] + bh[r];
  const int hw = HPOSH(r);            // f16 write slot for row r

  // zero both h buffers incl. pads (80 floats = 320 B each)
  if (tid < 80) ((float*)hsA)[tid] = 0.f;
  block_sync_lds();

  const float* xpb = xp + (size_t)b * RNN_S * RNN_H;

  // 4-deep fp32 prefetch, one register per unrolled body
  float p0 = xpb[0 * RNN_H + r];
  float p1 = xpb[1 * RNN_H + r];
  float p2 = xpb[2 * RNN_H + r];
  float p3 = xpb[3 * RNN_H + r];

#pragma unroll 1
  for (int t = 0; t < RNN_S; t += 4) {
    const int n0 = (t + 4 < RNN_S) ? t + 4 : RNN_S - 1;
    const int n1 = (t + 5 < RNN_S) ? t + 5 : RNN_S - 1;
    const int n2 = (t + 6 < RNN_S) ? t + 6 : RNN_S - 1;
    const int n3 = (t + 7 < RNN_S) ? t + 7 : RNN_S - 1;
    RNN_STEP(hsA, hsB, p0, n0)
    RNN_STEP(hsB, hsA, p1, n1)
    RNN_STEP(hsA, hsB, p2, n2)
    RNN_STEP(hsB, hsA, p3, n3)
  }
  // 2048 steps: last body writes hsA; trailing block_sync_lds made it visible.

  // fused FC: out[b][o] = sum_k hs[k] * Wfc[o][k] + bfc[o]
  if (tid < RNN_OUT) {
    float s = bfc[tid];
    const _Float16* hf = (const _Float16*)hsA;
#pragma unroll 4
    for (int k = 0; k < RNN_H; ++k)
      s = fmaf(Wfc[(size_t)tid * RNN_H + k], (float)hf[HPOSH(k)], s);
    out[b * RNN_OUT + tid] = s;
  }
}

extern "C" void kernel_launch(void* const* d_in, const int* in_sizes, int n_in,
                              void* d_out, int out_size, void* d_ws, size_t ws_size,
                              hipStream_t stream) {
  const float* x   = (const float*)d_in[0];
  const float* Wxh = (const float*)d_in[1];
  const float* bxh = (const float*)d_in[2];
  const float* Whh = (const float*)d_in[3];
  const float* bhh = (const float*)d_in[4];
  const float* bh  = (const float*)d_in[5];
  const float* Wfc = (const float*)d_in[6];
  const float* bfc = (const float*)d_in[7];
  float* out = (float*)d_out;
  float* xp  = (float*)d_ws;  // 131072*128*4 = 64 MiB

  xproj_gemm<<<dim3((RNN_B * RNN_S) / 128), dim3(256), 0, stream>>>(x, Wxh, bxh, xp);
  rnn_scan<<<dim3(RNN_B), dim3(512), 0, stream>>>(xp, Whh, bhh, bh, Wfc, bfc, out);
}